// Round 1
// baseline (339.343 us; speedup 1.0000x reference)
//
#include <hip/hip_runtime.h>
#include <math.h>

#define L_SEQ 384
#define E_DIM 512
#define NHEAD 8
#define NBH   16
#define HD    64

// ---------------------------------------------------------------------------
// GEMM: C = A @ B^T.  A: MxK row-major, Bm: NxK row-major.
// mode 0: C[m*N + f]   (plain row-major, used for final output projection)
// mode 1: head-scatter C[((b*8+h)*L + l)*64 + d]  with m=b*L+l, f=h*64+d
// blockIdx.z selects among B0/B1/B2 and offsets C by z*M*N (fused Q/K/V).
// Tile 64x64, BK=16, 256 threads, 4x4 outputs/thread.
// ---------------------------------------------------------------------------
__global__ __launch_bounds__(256) void gemm_abt(
    const float* __restrict__ A, const float* __restrict__ B0,
    const float* __restrict__ B1, const float* __restrict__ B2,
    float* __restrict__ C, int M, int N, int K, int mode)
{
  __shared__ float As[16][68];   // [k][m], pad 68 keeps 16B alignment + banks ok
  __shared__ float Bs[16][68];   // [k][n]

  const int tid = threadIdx.x;
  const int z = blockIdx.z;
  const float* Bm = (z == 0) ? B0 : (z == 1) ? B1 : B2;
  float* Cp = C + (size_t)z * (size_t)M * (size_t)N;

  const int m0 = blockIdx.y * 64;
  const int n0 = blockIdx.x * 64;
  const int tm = tid >> 4;    // 0..15 -> rows tm*4..tm*4+3
  const int tn = tid & 15;    // 0..15 -> cols tn*4..tn*4+3

  float acc[4][4];
  #pragma unroll
  for (int r = 0; r < 4; ++r)
    #pragma unroll
    for (int c = 0; c < 4; ++c) acc[r][c] = 0.f;

  for (int k0 = 0; k0 < K; k0 += 16) {
    #pragma unroll
    for (int p = 0; p < 4; ++p) {
      int idx = tid + p * 256;          // 0..1023 = 64 rows x 16 cols
      int row = idx >> 4, col = idx & 15;
      As[col][row] = A[(size_t)(m0 + row) * K + k0 + col];
      Bs[col][row] = Bm[(size_t)(n0 + row) * K + k0 + col];
    }
    __syncthreads();
    #pragma unroll
    for (int kk = 0; kk < 16; ++kk) {
      float4 a = *(const float4*)&As[kk][tm * 4];
      float4 b = *(const float4*)&Bs[kk][tn * 4];
      float av[4] = {a.x, a.y, a.z, a.w};
      float bv[4] = {b.x, b.y, b.z, b.w};
      #pragma unroll
      for (int r = 0; r < 4; ++r)
        #pragma unroll
        for (int c = 0; c < 4; ++c) acc[r][c] += av[r] * bv[c];
    }
    __syncthreads();
  }

  #pragma unroll
  for (int r = 0; r < 4; ++r) {
    int m = m0 + tm * 4 + r;
    int f0 = n0 + tn * 4;               // 4 consecutive cols, same head (f0%4==0)
    float4 val = make_float4(acc[r][0], acc[r][1], acc[r][2], acc[r][3]);
    if (mode == 0) {
      *(float4*)&Cp[(size_t)m * N + f0] = val;
    } else {
      int b = m / L_SEQ, l = m % L_SEQ;
      int h = f0 >> 6, d = f0 & 63;
      *(float4*)&Cp[((size_t)(b * NHEAD + h) * L_SEQ + l) * HD + d] = val;
    }
  }
}

// ---------------------------------------------------------------------------
// Fused pairwise core.
// Quaternion (w,x,y,z) stored in float4 fields (.x,.y,.z,.w).
// Thread = (bh, i, atom-group of 4).  4 threads (consecutive lanes) per (bh,i).
// Grid: (j_split=6, i_tiles=6, bh=16), block 256 = 64 i x 4 atom-groups.
// ---------------------------------------------------------------------------
__device__ __forceinline__ float4 hamilton(float4 a, float4 b) {
  float4 r;
  r.x = a.x * b.x - a.y * b.y - a.z * b.z - a.w * b.w;
  r.y = a.x * b.y + a.y * b.x + a.z * b.w - a.w * b.z;
  r.z = a.x * b.z - a.y * b.w + a.z * b.x + a.w * b.y;
  r.w = a.x * b.w + a.y * b.z - a.z * b.y + a.w * b.x;
  return r;
}

__global__ __launch_bounds__(256) void berry_main(
    const float* __restrict__ Q, const float* __restrict__ K,
    const float* __restrict__ V, const float* __restrict__ dde_w,
    const float* __restrict__ dde_b, float* __restrict__ CTX)
{
  __shared__ float kt[32][HD];
  __shared__ float vt[32][HD];

  const int tid = threadIdx.x;
  const int bh = blockIdx.z;
  const int i = blockIdx.y * 64 + (tid >> 2);
  const int ag = tid & 3;                  // atom group: atoms ag*4..ag*4+3 -> floats ag*16..
  const int jbase = blockIdx.x * 64;       // 6 chunks x 64 j

  // gate weights pre-scaled by 1/16 (folds the mean over 16 atoms)
  float gw[16];
  #pragma unroll
  for (int t = 0; t < 16; ++t) gw[t] = dde_w[t] * 0.0625f;
  float gb0 = dde_b[0], gb1 = dde_b[1], gb2 = dde_b[2], gb3 = dde_b[3];

  float4 qa[4], ctx[4];
  const float* qp = Q + ((size_t)(bh * L_SEQ + i) * HD + ag * 16);
  #pragma unroll
  for (int t = 0; t < 4; ++t) {
    qa[t] = ((const float4*)qp)[t];
    ctx[t] = make_float4(0.f, 0.f, 0.f, 0.f);
  }

  for (int jt = 0; jt < 64; jt += 32) {
    const int j0 = jbase + jt;
    #pragma unroll
    for (int p = 0; p < 2; ++p) {
      int idx = tid + p * 256;            // 0..511 = 32 j x 16 float4
      int jj = idx >> 4, fq = (idx & 15) * 4;
      size_t g = (size_t)(bh * L_SEQ + j0 + jj) * HD + fq;
      *(float4*)&kt[jj][fq] = *(const float4*)(K + g);
      *(float4*)&vt[jj][fq] = *(const float4*)(V + g);
    }
    __syncthreads();

    for (int jj = 0; jj < 32; ++jj) {
      float4 sp[4];
      float4 gs = make_float4(0.f, 0.f, 0.f, 0.f);
      #pragma unroll
      for (int a = 0; a < 4; ++a) {
        float4 kq = *(const float4*)&kt[jj][ag * 16 + a * 4];
        float4 h = hamilton(qa[a], kq);
        float d = h.x * h.x + h.y * h.y + h.z * h.z + h.w * h.w;
        float inv = __builtin_amdgcn_rcpf(__builtin_amdgcn_sqrtf(d) + 1e-6f);
        sp[a].x = h.x * inv; sp[a].y = h.y * inv;
        sp[a].z = h.z * inv; sp[a].w = h.w * inv;
        gs.x += sp[a].x; gs.y += sp[a].y; gs.z += sp[a].z; gs.w += sp[a].w;
      }
      // sum over the 4 atom-group lanes (16 atoms total); mean folded into gw
      gs.x += __shfl_xor(gs.x, 1, 64); gs.y += __shfl_xor(gs.y, 1, 64);
      gs.z += __shfl_xor(gs.z, 1, 64); gs.w += __shfl_xor(gs.w, 1, 64);
      gs.x += __shfl_xor(gs.x, 2, 64); gs.y += __shfl_xor(gs.y, 2, 64);
      gs.z += __shfl_xor(gs.z, 2, 64); gs.w += __shfl_xor(gs.w, 2, 64);

      float t0 = gb0 + gw[0]  * gs.x + gw[1]  * gs.y + gw[2]  * gs.z + gw[3]  * gs.w;
      float t1 = gb1 + gw[4]  * gs.x + gw[5]  * gs.y + gw[6]  * gs.z + gw[7]  * gs.w;
      float t2 = gb2 + gw[8]  * gs.x + gw[9]  * gs.y + gw[10] * gs.z + gw[11] * gs.w;
      float t3 = gb3 + gw[12] * gs.x + gw[13] * gs.y + gw[14] * gs.z + gw[15] * gs.w;
      float4 g;
      g.x = __builtin_amdgcn_rcpf(1.f + __expf(-t0));
      g.y = __builtin_amdgcn_rcpf(1.f + __expf(-t1));
      g.z = __builtin_amdgcn_rcpf(1.f + __expf(-t2));
      g.w = __builtin_amdgcn_rcpf(1.f + __expf(-t3));

      #pragma unroll
      for (int a = 0; a < 4; ++a) {
        float4 vq = *(const float4*)&vt[jj][ag * 16 + a * 4];
        float4 s;
        s.x = sp[a].x * g.x; s.y = sp[a].y * g.y;
        s.z = sp[a].z * g.z; s.w = sp[a].w * g.w;
        ctx[a].x += s.x * vq.x - s.y * vq.y - s.z * vq.z - s.w * vq.w;
        ctx[a].y += s.x * vq.y + s.y * vq.x + s.z * vq.w - s.w * vq.z;
        ctx[a].z += s.x * vq.z - s.y * vq.w + s.z * vq.x + s.w * vq.y;
        ctx[a].w += s.x * vq.w + s.y * vq.z - s.z * vq.y + s.w * vq.x;
      }
    }
    __syncthreads();
  }

  // scatter-accumulate into (b, l, e) layout for the output GEMM
  const int b = bh >> 3, h = bh & 7;
  float* cp = CTX + ((size_t)(b * L_SEQ + i) * E_DIM + h * HD + ag * 16);
  #pragma unroll
  for (int t = 0; t < 4; ++t) {
    atomicAdd(cp + t * 4 + 0, ctx[t].x);
    atomicAdd(cp + t * 4 + 1, ctx[t].y);
    atomicAdd(cp + t * 4 + 2, ctx[t].z);
    atomicAdd(cp + t * 4 + 3, ctx[t].w);
  }
}

// ---------------------------------------------------------------------------
extern "C" void kernel_launch(void* const* d_in, const int* in_sizes, int n_in,
                              void* d_out, int out_size, void* d_ws, size_t ws_size,
                              hipStream_t stream)
{
  const float* x     = (const float*)d_in[0];
  const float* Wq    = (const float*)d_in[1];
  const float* Wk    = (const float*)d_in[2];
  const float* Wv    = (const float*)d_in[3];
  const float* Wo    = (const float*)d_in[4];
  const float* dde_w = (const float*)d_in[5];
  const float* dde_b = (const float*)d_in[6];
  float* out = (float*)d_out;

  const size_t PROJ = (size_t)NBH * L_SEQ * HD;   // 393216 floats
  float* Qw  = (float*)d_ws;
  float* Kw  = Qw + PROJ;
  float* Vw  = Kw + PROJ;
  float* CTX = Vw + PROJ;                          // (b,l,e) layout, 393216 floats

  hipMemsetAsync(CTX, 0, PROJ * sizeof(float), stream);

  // Q/K/V projections (fused over grid.z), head-scatter output layout
  dim3 gp(E_DIM / 64, (2 * L_SEQ) / 64, 3);
  gemm_abt<<<gp, 256, 0, stream>>>(x, Wq, Wk, Wv, Qw, 2 * L_SEQ, E_DIM, E_DIM, 1);

  // fused pairwise core
  dim3 gm(6, 6, NBH);
  berry_main<<<gm, 256, 0, stream>>>(Qw, Kw, Vw, dde_w, dde_b, CTX);

  // output projection
  dim3 go(E_DIM / 64, (2 * L_SEQ) / 64, 1);
  gemm_abt<<<go, 256, 0, stream>>>(CTX, Wo, nullptr, nullptr, out, 2 * L_SEQ, E_DIM, E_DIM, 0);
}